// Round 8
// baseline (370.489 us; speedup 1.0000x reference)
//
#include <hip/hip_runtime.h>
#include <math.h>

typedef _Float16 h8f16 __attribute__((ext_vector_type(8)));
typedef _Float16 h4f16 __attribute__((ext_vector_type(4)));
typedef _Float16 h2f16 __attribute__((ext_vector_type(2)));
typedef float f32x4 __attribute__((ext_vector_type(4)));

#define MFMA16(a, b, c) __builtin_amdgcn_mfma_f32_16x16x32_f16((a), (b), (c), 0, 0, 0)

__device__ __forceinline__ float silu_f(float v) {
    return v * __builtin_amdgcn_rcpf(1.0f + __expf(-v));
}

// Bare barrier: writer-side LDS completion + s_barrier (no vmcnt drain).
__device__ __forceinline__ void bar_lds() {
    asm volatile("s_waitcnt lgkmcnt(0)" ::: "memory");
    __builtin_amdgcn_s_barrier();
    __builtin_amdgcn_sched_barrier(0);
}

// ---------------------------------------------------------------------------
// ODE mega-kernel v8: latency-minimized. 32 RK4 steps (reference-exact count).
// grid: 128 blocks (16 batch rows) x 256 threads = 4 waves -> 1 wave/SIMD
// (no VALU sharing between waves, minimal barrier skew).
// Wave q owns output cols [32q, 32q+32) of every layer.
//  - gamma folded into W1a, beta folded into b1; LN apply = x*inv + (-mu*inv)
//    (position-independent) in packed f16. Stats via fdot2 + 2 shfl (v6).
//  - All 65 lerped past tiles precomputed in LDS (zero global traffic in loop).
//  - v4 PERM pair layout: C-frag col pair (c, c+16) stored adjacently at
//    col' = 32q + 2*lrow + h  ->  4x ds_write_b32 per lane per phase.
//    Weight B-frags gathered with the inverse perm (sum over K invariant).
//  - z0 computed in the prologue (f32 exact).
// ---------------------------------------------------------------------------
__global__ __launch_bounds__(256, 1) void ode_kernel(
    const float* __restrict__ past,
    const float* __restrict__ xproj_w, const float* __restrict__ xproj_b,
    const float* __restrict__ z0_w, const float* __restrict__ z0_b,
    const float* __restrict__ ln_g, const float* __restrict__ ln_b,
    const float* __restrict__ w1, const float* __restrict__ b1,
    const float* __restrict__ w2, const float* __restrict__ b2,
    const float* __restrict__ w3, const float* __restrict__ b3,
    float* __restrict__ zbuf)
{
    __shared__ _Float16 bxAll[65][16][40];  // 83.2 KB lerped past tiles
    __shared__ _Float16 hbuf[16][136];      // LN input v (PERM cols)
    __shared__ _Float16 h1S[16][136];       // layer1 out (PERM cols)
    __shared__ _Float16 h2S[16][136];       // layer2 out (PERM cols)
    __shared__ float    pS[16][33];         // prologue
    __shared__ float    x0S[16][128];
    __shared__ float    zS0[16][129];

    const int tid  = threadIdx.x;
    const int wq   = tid >> 6;
    const int lane = tid & 63;
    const int lrow = lane & 15;
    const int lhi  = lane >> 4;
    const int b0   = blockIdx.x * 16;
    const int koff = lhi * 8;

    // stored offset m = lhi*8+j within a 32-block <-> true k = ks*32 + lhi*4 + PERM[j]
    const int PERM[8] = {0, 16, 1, 17, 2, 18, 3, 19};

    // ---- weights into register B-fragments (PERM gather; gamma folded) ----
    h8f16 w1f[2][4], wcf[2], w2f[2][4], w3f[2][4];
    float b1t[2], b2r[2], b3r[2];
#pragma unroll
    for (int nt = 0; nt < 2; ++nt) {
        const int n = wq * 32 + nt * 16 + lrow;
#pragma unroll
        for (int ks = 0; ks < 4; ++ks) {
            const float* s1 = w1 + n * 256 + ks * 32 + lhi * 4;
            const float* g1 = ln_g + ks * 32 + lhi * 4;
            const float* s2 = w2 + n * 128 + ks * 32 + lhi * 4;
            const float* s3 = w3 + n * 128 + ks * 32 + lhi * 4;
            h8f16 v1, v2, v3;
#pragma unroll
            for (int j = 0; j < 8; ++j) {
                v1[j] = (_Float16)(s1[PERM[j]] * g1[PERM[j]]);
                v2[j] = (_Float16)s2[PERM[j]];
                v3[j] = (_Float16)s3[PERM[j]];
            }
            w1f[nt][ks] = v1; w2f[nt][ks] = v2; w3f[nt][ks] = v3;
        }
        // Wc = W1b @ xproj_w (straight); bc = W1b @ xproj_b; bb = W1a @ ln_b
        float wc[8] = {0, 0, 0, 0, 0, 0, 0, 0};
        float bc = 0.0f, bb = 0.0f;
        const float* w1a = w1 + n * 256;
        const float* w1b = w1a + 128;
#pragma unroll 4
        for (int k = 0; k < 128; ++k) {
            const float a = w1b[k];
            bc += a * xproj_b[k];
            bb += w1a[k] * ln_b[k];
            const float* xr = xproj_w + k * 32 + koff;
#pragma unroll
            for (int j = 0; j < 8; ++j) wc[j] += a * xr[j];
        }
        h8f16 v;
#pragma unroll
        for (int j = 0; j < 8; ++j) v[j] = (_Float16)wc[j];
        wcf[nt] = v;
        b1t[nt] = b1[n] + bc + bb;
        b2r[nt] = b2[n]; b3r[nt] = b3[n];
    }

    // ---- prologue: z0 = (past[:,0,:] @ xw.T + xb) @ z0w.T + z0b (f32) ----
    for (int i = tid; i < 512; i += 256)
        pS[i >> 5][i & 31] = past[(long)(b0 + (i >> 5)) * 16384 + (i & 31)];
    __syncthreads();
    {
        const int r  = tid >> 4;
        const int c0 = (tid & 15) * 8;
#pragma unroll
        for (int cc = 0; cc < 8; ++cc) {
            const int kc = c0 + cc;
            float s = xproj_b[kc];
            const float* xr = xproj_w + kc * 32;
#pragma unroll
            for (int c = 0; c < 32; ++c) s += pS[r][c] * xr[c];
            x0S[r][kc] = s;
        }
    }
    __syncthreads();
    {
        const int nn = tid & 127;
        const int r0 = (tid >> 7) * 8;
        for (int p = 0; p < 8; ++p) {
            const int r = r0 + p;
            float s = z0_b[nn];
            const float* zr = z0_w + nn * 128;
            for (int k = 0; k < 128; ++k) s += x0S[r][k] * zr[k];
            zS0[r][nn] = s;
        }
    }

    // ---- preload ALL 65 lerped bx tiles into LDS ----
    for (int flat = tid; flat < 65 * 128; flat += 256) {
        const int e  = flat >> 7;
        const int u  = flat & 127;
        const int r  = u >> 3;
        const int c  = (u & 7) * 4;
        const float pos = (float)e * 7.984375f;     // e*(511/64), exact
        const int i0 = (int)pos;
        const int i1 = (i0 < 511) ? i0 + 1 : 511;
        const float w = pos - (float)i0;
        const f32x4 a0 = *(const f32x4*)(past + ((long)(b0 + r) * 512 + i0) * 32 + c);
        const f32x4 a1 = *(const f32x4*)(past + ((long)(b0 + r) * 512 + i1) * 32 + c);
        h4f16 v;
#pragma unroll
        for (int j = 0; j < 4; ++j) v[j] = (_Float16)((1.0f - w) * a0[j] + w * a1[j]);
        *(h4f16*)&bxAll[e][r][c] = v;
    }
    __syncthreads();

    // ---- z cached per-lane in C-frag layout: rows 4*lhi+j, cols (cA, cB) ----
    const int cA = wq * 32 + lrow, cB = cA + 16;
    const int pc = wq * 32 + 2 * lrow;      // PERM pair col
    float zc[2][4];
#pragma unroll
    for (int j = 0; j < 4; ++j) {
        zc[0][j] = zS0[4 * lhi + j][cA];
        zc[1][j] = zS0[4 * lhi + j][cB];
        *(h2f16*)&hbuf[4 * lhi + j][pc] = (h2f16){(_Float16)zc[0][j], (_Float16)zc[1][j]};
    }

    f32x4 krk[2];
    krk[0] = (f32x4){0, 0, 0, 0}; krk[1] = (f32x4){0, 0, 0, 0};
    const float DT = 1.0f / 32.0f;
    const h2f16 one2 = {(_Float16)1.0f, (_Float16)1.0f};

    // ---- phases ----
    auto phaseA = [&](int e) {
        h8f16 xf[4];
#pragma unroll
        for (int ks = 0; ks < 4; ++ks)
            xf[ks] = *(const h8f16*)&hbuf[lrow][ks * 32 + koff];
        // LN stats via fdot2 (order-invariant under PERM)
        float s0 = 0.f, s1 = 0.f, q0 = 0.f, q1 = 0.f;
#pragma unroll
        for (int ks = 0; ks < 4; ++ks) {
#pragma unroll
            for (int p = 0; p < 4; ++p) {
                const h2f16 x2 = {xf[ks][2 * p], xf[ks][2 * p + 1]};
                if (p & 1) {
                    s1 = __builtin_amdgcn_fdot2(x2, one2, s1, false);
                    q1 = __builtin_amdgcn_fdot2(x2, x2, q1, false);
                } else {
                    s0 = __builtin_amdgcn_fdot2(x2, one2, s0, false);
                    q0 = __builtin_amdgcn_fdot2(x2, x2, q0, false);
                }
            }
        }
        float s = s0 + s1, q = q0 + q1;
        s += __shfl_xor(s, 16); q += __shfl_xor(q, 16);
        s += __shfl_xor(s, 32); q += __shfl_xor(q, 32);
        const float mu  = s * (1.0f / 128.0f);
        const float var = q * (1.0f / 128.0f) - mu * mu;
        const float inv = 1.0f / sqrtf(var + 1e-5f);
        const _Float16 ih = (_Float16)inv;
        const _Float16 mh = (_Float16)(-mu * inv);
        h8f16 ip, mp;
#pragma unroll
        for (int j = 0; j < 8; ++j) { ip[j] = ih; mp[j] = mh; }
        const h8f16 bx = *(const h8f16*)&bxAll[e][lrow][koff];
        f32x4 a0 = {0, 0, 0, 0}, a1 = {0, 0, 0, 0};
#pragma unroll
        for (int ks = 0; ks < 4; ++ks) {
            const h8f16 az = xf[ks] * ip + mp;   // packed f16 LN-apply
            a0 = MFMA16(az, w1f[0][ks], a0);
            a1 = MFMA16(az, w1f[1][ks], a1);
        }
        a0 = MFMA16(bx, wcf[0], a0);
        a1 = MFMA16(bx, wcf[1], a1);
#pragma unroll
        for (int j = 0; j < 4; ++j) {
            const _Float16 o0 = (_Float16)silu_f(a0[j] + b1t[0]);
            const _Float16 o1 = (_Float16)silu_f(a1[j] + b1t[1]);
            *(h2f16*)&h1S[4 * lhi + j][pc] = (h2f16){o0, o1};
        }
    };
    auto phaseB = [&]() {
        f32x4 a0 = {0, 0, 0, 0}, a1 = {0, 0, 0, 0};
#pragma unroll
        for (int ks = 0; ks < 4; ++ks) {
            const h8f16 a = *(const h8f16*)&h1S[lrow][ks * 32 + koff];
            a0 = MFMA16(a, w2f[0][ks], a0);
            a1 = MFMA16(a, w2f[1][ks], a1);
        }
#pragma unroll
        for (int j = 0; j < 4; ++j) {
            const _Float16 o0 = (_Float16)silu_f(a0[j] + b2r[0]);
            const _Float16 o1 = (_Float16)silu_f(a1[j] + b2r[1]);
            *(h2f16*)&h2S[4 * lhi + j][pc] = (h2f16){o0, o1};
        }
    };

#pragma unroll 1
    for (int step = 0; step < 32; ++step) {
#pragma unroll 1
        for (int sub = 0; sub < 4; ++sub) {
            const int e = 2 * step + ((sub + 1) >> 1);
            phaseA(e);  bar_lds();
            phaseB();   bar_lds();
            {   // phase C: layer3 + RK4 + v_next
                f32x4 a0 = {0, 0, 0, 0}, a1 = {0, 0, 0, 0};
#pragma unroll
                for (int ks = 0; ks < 4; ++ks) {
                    const h8f16 a = *(const h8f16*)&h2S[lrow][ks * 32 + koff];
                    a0 = MFMA16(a, w3f[0][ks], a0);
                    a1 = MFMA16(a, w3f[1][ks], a1);
                }
#pragma unroll
                for (int j = 0; j < 4; ++j) {
                    const float k0v = a0[j] + b3r[0];
                    const float k1v = a1[j] + b3r[1];
                    float v0, v1;
                    if (sub == 0) {
                        krk[0][j] = k0v; krk[1][j] = k1v;
                        v0 = zc[0][j] + 0.5f * DT * k0v;
                        v1 = zc[1][j] + 0.5f * DT * k1v;
                    } else if (sub == 1) {
                        krk[0][j] += 2.0f * k0v; krk[1][j] += 2.0f * k1v;
                        v0 = zc[0][j] + 0.5f * DT * k0v;
                        v1 = zc[1][j] + 0.5f * DT * k1v;
                    } else if (sub == 2) {
                        krk[0][j] += 2.0f * k0v; krk[1][j] += 2.0f * k1v;
                        v0 = zc[0][j] + DT * k0v;
                        v1 = zc[1][j] + DT * k1v;
                    } else {
                        zc[0][j] += (DT / 6.0f) * (krk[0][j] + k0v);
                        zc[1][j] += (DT / 6.0f) * (krk[1][j] + k1v);
                        v0 = zc[0][j];
                        v1 = zc[1][j];
                    }
                    *(h2f16*)&hbuf[4 * lhi + j][pc] = (h2f16){(_Float16)v0, (_Float16)v1};
                }
            }
            bar_lds();
        }
    }

    // ---- store final z ----
#pragma unroll
    for (int j = 0; j < 4; ++j) {
        const long rb = (long)(b0 + 4 * lhi + j) * 128;
        zbuf[rb + cA] = zc[0][j];
        zbuf[rb + cB] = zc[1][j];
    }
}

// ---------------------------------------------------------------------------
// hcat = [x_t flat (3072) | cond (128) | time-emb (128)] as f16
// ---------------------------------------------------------------------------
__global__ __launch_bounds__(256) void hcat_kernel(
    const float* __restrict__ x_t, const float* __restrict__ cond,
    const int* __restrict__ tvals, _Float16* __restrict__ hcat)
{
    const int gid = blockIdx.x * 256 + threadIdx.x;
    const int b  = gid / 416;
    const int j0 = (gid % 416) * 8;
    h8f16 v;
    if (j0 < 3072) {
        const float* s = x_t + (long)b * 3072 + j0;
#pragma unroll
        for (int j = 0; j < 8; ++j) v[j] = (_Float16)s[j];
    } else if (j0 < 3200) {
        const float* s = cond + (long)b * 128 + (j0 - 3072);
#pragma unroll
        for (int j = 0; j < 8; ++j) v[j] = (_Float16)s[j];
    } else {
        const float tv = (float)tvals[b];
#pragma unroll
        for (int j = 0; j < 8; ++j) {
            const int jj  = j0 - 3200 + j;
            const int idx = (jj < 64) ? jj : jj - 64;
            const float fr = expf(-9.210340371976184f * (float)idx * (1.0f / 63.0f));
            const float a  = tv * fr;
            v[j] = (_Float16)((jj < 64) ? sinf(a) : cosf(a));
        }
    }
    *(h8f16*)&hcat[(long)b * 3328 + j0] = v;
}

// ---------------------------------------------------------------------------
// Generic f16-MFMA GEMM: out(M,N) = [silu](A(M,K) @ W(N,K).T + bias)
// ---------------------------------------------------------------------------
template <bool SILU, bool OUT_F16>
__global__ __launch_bounds__(256) void gemm_f16(
    const _Float16* __restrict__ A, const float* __restrict__ W,
    const float* __restrict__ bias, void* __restrict__ out,
    int M, int N, int K)
{
    __shared__ _Float16 aS[64][40];
    __shared__ _Float16 wS[64][40];
    const int mb = blockIdx.x * 64, nb = blockIdx.y * 64;
    const int tid = threadIdx.x, lane = tid & 63, wq = tid >> 6;
    const int lrow = lane & 15, lhi = lane >> 4;
    f32x4 acc[4];
#pragma unroll
    for (int nt = 0; nt < 4; ++nt) acc[nt] = (f32x4){0, 0, 0, 0};

    const int sr = tid >> 2;
    const int sk = (tid & 3) * 8;

    for (int k0 = 0; k0 < K; k0 += 32) {
        {
            h8f16 v = *(const h8f16*)&A[(long)(mb + sr) * K + k0 + sk];
            *(h8f16*)&aS[sr][sk] = v;
        }
        {
            const float* s = &W[(long)(nb + sr) * K + k0 + sk];
            h8f16 v;
#pragma unroll
            for (int j = 0; j < 8; ++j) v[j] = (_Float16)s[j];
            *(h8f16*)&wS[sr][sk] = v;
        }
        __syncthreads();
        h8f16 a = *(const h8f16*)&aS[wq * 16 + lrow][lhi * 8];
#pragma unroll
        for (int nt = 0; nt < 4; ++nt) {
            h8f16 bfr = *(const h8f16*)&wS[nt * 16 + lrow][lhi * 8];
            acc[nt] = MFMA16(a, bfr, acc[nt]);
        }
        __syncthreads();
    }

#pragma unroll
    for (int nt = 0; nt < 4; ++nt) {
        const int cc = nb + nt * 16 + lrow;
        const float bv = bias[cc];
#pragma unroll
        for (int j = 0; j < 4; ++j) {
            const int rr = mb + wq * 16 + lhi * 4 + j;
            float v = acc[nt][j] + bv;
            if (SILU) v = silu_f(v);
            if (OUT_F16) ((_Float16*)out)[(long)rr * N + cc] = (_Float16)v;
            else         ((float*)out)[(long)rr * N + cc] = v;
        }
    }
}

// ---------------------------------------------------------------------------
extern "C" void kernel_launch(void* const* d_in, const int* in_sizes, int n_in,
                              void* d_out, int out_size, void* d_ws, size_t ws_size,
                              hipStream_t stream)
{
    const float* x_t     = (const float*)d_in[0];
    const float* past    = (const float*)d_in[1];
    const int*   tvals   = (const int*)d_in[2];
    const float* xproj_w = (const float*)d_in[3];
    const float* xproj_b = (const float*)d_in[4];
    const float* z0_w    = (const float*)d_in[5];
    const float* z0_b    = (const float*)d_in[6];
    const float* ln_g    = (const float*)d_in[7];
    const float* ln_b    = (const float*)d_in[8];
    const float* w1      = (const float*)d_in[9];
    const float* b1      = (const float*)d_in[10];
    const float* w2      = (const float*)d_in[11];
    const float* b2      = (const float*)d_in[12];
    const float* w3      = (const float*)d_in[13];
    const float* b3      = (const float*)d_in[14];
    const float* fw1     = (const float*)d_in[15];
    const float* fb1     = (const float*)d_in[16];
    const float* fw2     = (const float*)d_in[17];
    const float* fb2     = (const float*)d_in[18];
    const float* fw3     = (const float*)d_in[19];
    const float* fb3     = (const float*)d_in[20];

    char* ws = (char*)d_ws;
    float*     zbuf = (float*)ws;                               // 1 MB
    _Float16*  hcat = (_Float16*)(ws + (1 << 20));              // 13.63 MB
    _Float16*  h1   = (_Float16*)(ws + 15 * (1 << 20));         // 1 MB
    _Float16*  h2   = (_Float16*)(ws + 16 * (1 << 20));         // 1 MB

    ode_kernel<<<128, 256, 0, stream>>>(past, xproj_w, xproj_b, z0_w, z0_b,
                                        ln_g, ln_b, w1, b1, w2, b2, w3, b3, zbuf);

    hcat_kernel<<<(2048 * 416) / 256, 256, 0, stream>>>(x_t, zbuf, tvals, hcat);

    gemm_f16<true,  true ><<<dim3(32, 4),  256, 0, stream>>>(hcat, fw1, fb1, h1, 2048, 256, 3328);
    gemm_f16<true,  true ><<<dim3(32, 4),  256, 0, stream>>>(h1,   fw2, fb2, h2, 2048, 256, 256);
    gemm_f16<false, false><<<dim3(32, 48), 256, 0, stream>>>(h2,   fw3, fb3, d_out, 2048, 3072, 256);
}